// Round 2
// baseline (3402.859 us; speedup 1.0000x reference)
//
#include <hip/hip_runtime.h>
#include <cstdint>

typedef __attribute__((ext_vector_type(8)))  __bf16 v8bf;
typedef __attribute__((ext_vector_type(16))) float  v16f;
typedef unsigned short ushort_t;

#define N_TOK  65536
#define DIM    256
#define K_CB   4096
#define BN     64          // tokens per block
#define KC     512         // codes per kc-iter (8 waves x 64)
#define NKCI   8           // K_CB / KC
#define TOTCH  136         // NKCI * 17 chunks (16 data + 1 b2-chunk per kc-iter)
#define MARGIN_S 2.0e-4f   // s-space margin == 4e-4 dist-space

#define MFMA(a,b,c) __builtin_amdgcn_mfma_f32_32x32x16_bf16(a,b,c,0,0,0)

static __device__ __forceinline__ void gl_lds16(const void* g, void* l) {
    __builtin_amdgcn_global_load_lds(
        (const __attribute__((address_space(1))) unsigned int*)g,
        (__attribute__((address_space(3))) unsigned int*)l, 16, 0, 0);
}

// ---------------------------------------------------------------- b2 = ||c_k||^2
__global__ void b2_kernel(const float* __restrict__ cb, float* __restrict__ b2) {
    int gid = blockIdx.x * blockDim.x + threadIdx.x;
    int w = gid >> 6, lane = gid & 63;
    if (w >= K_CB) return;
    float4 v = reinterpret_cast<const float4*>(cb + (size_t)w * DIM)[lane];
    float s = (v.x * v.x + v.y * v.y) + (v.z * v.z + v.w * v.w);
#pragma unroll
    for (int off = 1; off < 64; off <<= 1) s += __shfl_xor(s, off, 64);
    if (lane == 0) b2[w] = s;
}

// ---------------------------------------------------------------- pack cb -> bf16 hi/lo panels
// ws chunk layout (32 KB each, 136 chunks): [wid 8][hi 2KB: [dgrp 2][64 codes][8 d]][lo 2KB]
__global__ void pack_cb(const float* __restrict__ cb, ushort_t* __restrict__ cbws) {
    int gid = blockIdx.x * 256 + threadIdx.x;          // 0..131071
    int k = gid >> 5, grp = gid & 31;                  // grp = d/8
    int ci = grp >> 1, dgrp = grp & 1;
    int kci = k >> 9, code = k & 511;
    int wid_s = code >> 6, cloc = code & 63;
    const float* src = cb + (size_t)k * DIM + grp * 8;
    float4 v0 = *(const float4*)(src);
    float4 v1 = *(const float4*)(src + 4);
    float f[8] = {v0.x, v0.y, v0.z, v0.w, v1.x, v1.y, v1.z, v1.w};
    v8bf hv, lv;
#pragma unroll
    for (int e = 0; e < 8; ++e) {
        __bf16 h = (__bf16)f[e];
        hv[e] = h;
        lv[e] = (__bf16)(f[e] - (float)h);
    }
    size_t base = ((size_t)(kci * 17 + ci)) * 16384 + wid_s * 2048 + dgrp * 512 + cloc * 8;
    *(v8bf*)(cbws + base)        = hv;
    *(v8bf*)(cbws + base + 1024) = lv;
}

// ---------------------------------------------------------------- pack b2 chunk (ci = 16)
__global__ void pack_b2(const float* __restrict__ b2, ushort_t* __restrict__ cbws) {
    int k = blockIdx.x * 256 + threadIdx.x;
    if (k >= K_CB) return;
    int kci = k >> 9, code = k & 511;
    int wid_s = code >> 6, cloc = code & 63;
    float v = -0.5f * b2[k];
    __bf16 h = (__bf16)v;
    __bf16 l = (__bf16)(v - (float)h);
    v8bf hv, zv;
#pragma unroll
    for (int e = 0; e < 8; ++e) { hv[e] = (__bf16)0.0f; zv[e] = (__bf16)0.0f; }
    hv[0] = h; hv[1] = l;
    size_t base = ((size_t)(kci * 17 + 16)) * 16384 + wid_s * 2048 + cloc * 8;
    *(v8bf*)(cbws + base)        = hv;   // hi dgrp0: k-slots 0,1 carry -b2/2 hi/lo
    *(v8bf*)(cbws + base + 512)  = zv;   // hi dgrp1
    *(v8bf*)(cbws + base + 1024) = zv;   // lo dgrp0
    *(v8bf*)(cbws + base + 1536) = zv;   // lo dgrp1
}

// ---------------------------------------------------------------- fused MFMA dist+argmax(s)
// s[n][k] = dot(x_n, c_k) - b2[k]/2 ; maximize s == minimize squared distance.
__global__ __launch_bounds__(512, 2) void argmin_kernel(
    const float* __restrict__ x, const ushort_t* __restrict__ cbws,
    int* __restrict__ bestIdx, int* __restrict__ flagCnt, int* __restrict__ flagList)
{
    __shared__ __align__(16) ushort_t Xh[32 * 64 * 8];   // 32 KB: [dgrp 32][token 64][8 d]
    __shared__ __align__(16) ushort_t Xl[32 * 64 * 8];   // 32 KB
    __shared__ __align__(16) ushort_t Cs[3 * 8 * 2048];  // 96 KB: [ring 3][wid 8][4 KB slice]

    const int tid   = threadIdx.x;
    const int wid   = tid >> 6;
    const int lane  = tid & 63;
    const int l31   = lane & 31;
    const int lhalf = lane >> 5;
    const int n0    = blockIdx.x * BN;

    // ---- stage x tile (once): fp32 -> hi/lo bf16, d-subtiled
    {
        const int token = tid >> 3, dseg = tid & 7;
        const float4* xr = (const float4*)(x + (size_t)(n0 + token) * DIM + dseg * 32);
#pragma unroll
        for (int sgrp = 0; sgrp < 4; ++sgrp) {
            float4 a = xr[2 * sgrp], b = xr[2 * sgrp + 1];
            float f[8] = {a.x, a.y, a.z, a.w, b.x, b.y, b.z, b.w};
            v8bf hv, lv;
#pragma unroll
            for (int e = 0; e < 8; ++e) {
                __bf16 h = (__bf16)f[e];
                hv[e] = h; lv[e] = (__bf16)(f[e] - (float)h);
            }
            int off = ((dseg * 4 + sgrp) * 64 + token) * 8;
            *(v8bf*)(Xh + off) = hv;
            *(v8bf*)(Xl + off) = lv;
        }
    }

    // constant B-frag for the b2 chunk: B[k][n] = 1.0 at k-slots 0,1
    v8bf b17;
#pragma unroll
    for (int e = 0; e < 8; ++e) b17[e] = (__bf16)0.0f;
    if (lhalf == 0) { b17[0] = (__bf16)1.0f; b17[1] = (__bf16)1.0f; }

    const char* wsrc = (const char*)cbws + (size_t)wid * 4096 + (size_t)lane * 16;
    char* csb = (char*)Cs + (size_t)wid * 4096;
#define STAGE(c, s) do { \
        const char* sp_ = wsrc + (size_t)(c) * 32768; \
        char* dp_ = csb + (size_t)(s) * 32768; \
        gl_lds16(sp_, dp_); gl_lds16(sp_ + 1024, dp_ + 1024); \
        gl_lds16(sp_ + 2048, dp_ + 2048); gl_lds16(sp_ + 3072, dp_ + 3072); } while (0)

    asm volatile("s_waitcnt vmcnt(0)" ::: "memory");   // clean vmcnt baseline (x loads drained)
    STAGE(0, 0); STAGE(1, 1); STAGE(2, 2);
    asm volatile("s_waitcnt lgkmcnt(0)" ::: "memory"); // x ds_writes done
    __builtin_amdgcn_s_barrier();                      // Xh/Xl visible to all waves
    __builtin_amdgcn_sched_barrier(0);

    v16f vzero;
#pragma unroll
    for (int r = 0; r < 16; ++r) vzero[r] = 0.0f;
    v16f acc_h[2][2], acc_x[2][2];
#pragma unroll
    for (int a = 0; a < 2; ++a)
#pragma unroll
        for (int b = 0; b < 2; ++b) { acc_h[a][b] = vzero; acc_x[a][b] = vzero; }

    float b1d[2] = {-3.0e38f, -3.0e38f}, b2d[2] = {-3.0e38f, -3.0e38f};
    int   b1i[2] = {0x7fffffff, 0x7fffffff};
    const int klh = 4 * lhalf;

    int g = 0, slot = 0;
#pragma unroll 1
    for (int kci = 0; kci < NKCI; ++kci) {
#pragma unroll 1
        for (int ci = 0; ci < 17; ++ci, ++g) {
            // wait for own chunk g (counted vmcnt; waves are barrier-free)
            if (g <= 133)      asm volatile("s_waitcnt vmcnt(8)" ::: "memory");
            else if (g == 134) asm volatile("s_waitcnt vmcnt(4)" ::: "memory");
            else               asm volatile("s_waitcnt vmcnt(0)" ::: "memory");

            const ushort_t* sl = Cs + ((size_t)slot * 8 + wid) * 2048;
            const int aoff = lhalf * 512 + l31 * 8;
            if (ci < 16) {
                v8bf ah0 = *(const v8bf*)(sl + aoff);
                v8bf ah1 = *(const v8bf*)(sl + aoff + 256);
                v8bf al0 = *(const v8bf*)(sl + 1024 + aoff);
                v8bf al1 = *(const v8bf*)(sl + 1024 + aoff + 256);
                const int boff = ((ci * 2 + lhalf) * 64 + l31) * 8;
                v8bf bh0 = *(const v8bf*)(Xh + boff);
                v8bf bh1 = *(const v8bf*)(Xh + boff + 256);
                v8bf bl0 = *(const v8bf*)(Xl + boff);
                v8bf bl1 = *(const v8bf*)(Xl + boff + 256);
                acc_h[0][0] = MFMA(ah0, bh0, acc_h[0][0]);
                acc_h[0][1] = MFMA(ah0, bh1, acc_h[0][1]);
                acc_h[1][0] = MFMA(ah1, bh0, acc_h[1][0]);
                acc_h[1][1] = MFMA(ah1, bh1, acc_h[1][1]);
                acc_x[0][0] = MFMA(ah0, bl0, acc_x[0][0]);
                acc_x[0][0] = MFMA(al0, bh0, acc_x[0][0]);
                acc_x[0][1] = MFMA(ah0, bl1, acc_x[0][1]);
                acc_x[0][1] = MFMA(al0, bh1, acc_x[0][1]);
                acc_x[1][0] = MFMA(ah1, bl0, acc_x[1][0]);
                acc_x[1][0] = MFMA(al1, bh0, acc_x[1][0]);
                acc_x[1][1] = MFMA(ah1, bl1, acc_x[1][1]);
                acc_x[1][1] = MFMA(al1, bh1, acc_x[1][1]);
            } else {   // b2 chunk: adds -b2[k]/2 (hi+lo in k-slots 0,1) to every column
                v8bf ah0 = *(const v8bf*)(sl + aoff);
                v8bf ah1 = *(const v8bf*)(sl + aoff + 256);
                acc_h[0][0] = MFMA(ah0, b17, acc_h[0][0]);
                acc_h[0][1] = MFMA(ah0, b17, acc_h[0][1]);
                acc_h[1][0] = MFMA(ah1, b17, acc_h[1][0]);
                acc_h[1][1] = MFMA(ah1, b17, acc_h[1][1]);
            }
            __builtin_amdgcn_sched_barrier(0);
            if (g <= 132) STAGE(g + 3, slot);   // refill the slot just consumed
            slot = (slot == 2) ? 0 : slot + 1;
        }
        // ---- fold this kc-chunk into running top-2 (pure registers), reset acc
        const int kbase = kci * KC + wid * 64 + klh;
#pragma unroll
        for (int fm = 0; fm < 2; ++fm)
#pragma unroll
        for (int j = 0; j < 2; ++j) {
            v16f s = acc_h[fm][j] + acc_x[fm][j];
#pragma unroll
            for (int r = 0; r < 16; ++r) {
                float sv = s[r];
                int k = kbase + fm * 32 + ((r & 3) + 8 * (r >> 2));
                bool better = (sv > b1d[j]) || (sv == b1d[j] && k < b1i[j]);
                b2d[j] = better ? b1d[j] : fmaxf(b2d[j], sv);
                b1d[j] = better ? sv : b1d[j];
                b1i[j] = better ? k : b1i[j];
            }
            acc_h[fm][j] = vzero;
            acc_x[fm][j] = vzero;
        }
    }

    // ---- merge lane halves (same token lives in lane and lane^32)
#pragma unroll
    for (int j = 0; j < 2; ++j) {
        float o1 = __shfl_xor(b1d[j], 32);
        float o2 = __shfl_xor(b2d[j], 32);
        int   oi = __shfl_xor(b1i[j], 32);
        bool ow = (o1 > b1d[j]) || (o1 == b1d[j] && oi < b1i[j]);
        float nb2 = fmaxf(fminf(b1d[j], o1), fmaxf(b2d[j], o2));
        b1i[j] = ow ? oi : b1i[j];
        b1d[j] = fmaxf(b1d[j], o1);
        b2d[j] = nb2;
    }

    __syncthreads();
    float* f1 = (float*)Xh;          // [8 waves][64 tokens]
    float* f2 = f1 + 512;
    int*   fi = (int*)(f2 + 512);
    if (lane < 32) {
#pragma unroll
        for (int j = 0; j < 2; ++j) {
            int idx = wid * 64 + j * 32 + l31;
            f1[idx] = b1d[j]; f2[idx] = b2d[j]; fi[idx] = b1i[j];
        }
    }
    __syncthreads();
    if (tid < BN) {
        float s1 = -3.0e38f, s2 = -3.0e38f; int si = 0x7fffffff;
#pragma unroll
        for (int w = 0; w < 8; ++w) {
            float c1 = f1[w * 64 + tid], c2 = f2[w * 64 + tid];
            int  ci1 = fi[w * 64 + tid];
            bool ow = (c1 > s1) || (c1 == s1 && ci1 < si);
            float nb2 = fmaxf(fminf(s1, c1), fmaxf(s2, c2));
            si = ow ? ci1 : si; s1 = fmaxf(s1, c1); s2 = nb2;
        }
        int n = n0 + tid;
        bestIdx[n] = si;
        if (s1 - s2 < MARGIN_S) {            // dist gap < 4e-4 -> exact re-resolve
            int pos = atomicAdd(flagCnt, 1);
            flagList[pos] = n;
        }
    }
}

// ---------------------------------------------------------------- fp64 exact refine
__global__ void refine_kernel(const float* __restrict__ x, const float* __restrict__ cb,
                              const int* __restrict__ flagCnt, const int* __restrict__ flagList,
                              int* __restrict__ bestIdx)
{
    __shared__ float  xr[DIM];
    __shared__ double rd[256];
    __shared__ int    ri[256];
    const int tid = threadIdx.x;
    const int cnt = *flagCnt;
    for (int f = blockIdx.x; f < cnt; f += gridDim.x) {
        const int n = flagList[f];
        __syncthreads();
        if (tid < DIM / 4) {
            float4 v = reinterpret_cast<const float4*>(x + (size_t)n * DIM)[tid];
            xr[tid * 4 + 0] = v.x; xr[tid * 4 + 1] = v.y;
            xr[tid * 4 + 2] = v.z; xr[tid * 4 + 3] = v.w;
        }
        __syncthreads();
        double best = 1e300; int bi = K_CB;
        for (int k = tid; k < K_CB; k += 256) {
            const float* crow = cb + (size_t)k * DIM;
            double dot = 0.0, nb = 0.0;
            for (int d = 0; d < DIM; d += 4) {
                float4 cv = *reinterpret_cast<const float4*>(crow + d);
                dot += (double)cv.x * xr[d]     + (double)cv.y * xr[d + 1]
                     + (double)cv.z * xr[d + 2] + (double)cv.w * xr[d + 3];
                nb  += (double)cv.x * cv.x + (double)cv.y * cv.y
                     + (double)cv.z * cv.z + (double)cv.w * cv.w;
            }
            double dist = nb - 2.0 * dot;
            if (dist < best || (dist == best && k < bi)) { best = dist; bi = k; }
        }
        rd[tid] = best; ri[tid] = bi;
        __syncthreads();
        for (int s = 128; s > 0; s >>= 1) {
            if (tid < s) {
                double od = rd[tid + s]; int oi = ri[tid + s];
                if (od < rd[tid] || (od == rd[tid] && oi < ri[tid])) { rd[tid] = od; ri[tid] = oi; }
            }
            __syncthreads();
        }
        if (tid == 0) bestIdx[n] = ri[0];
        __syncthreads();
    }
}

// ---------------------------------------------------------------- gather out rows
__global__ void gather_kernel(const float* __restrict__ cb, const int* __restrict__ bestIdx,
                              float* __restrict__ out)
{
    int t = blockIdx.x * 256 + threadIdx.x;
    int n = t >> 6, f4 = t & 63;
    int k = bestIdx[n];
    reinterpret_cast<float4*>(out)[t] =
        reinterpret_cast<const float4*>(cb + (size_t)k * DIM)[f4];
}

extern "C" void kernel_launch(void* const* d_in, const int* in_sizes, int n_in,
                              void* d_out, int out_size, void* d_ws, size_t ws_size,
                              hipStream_t stream)
{
    const float* x  = (const float*)d_in[0];
    const float* cb = (const float*)d_in[1];
    float* out = (float*)d_out;

    char* ws = (char*)d_ws;
    ushort_t* cbws   = (ushort_t*)ws;                       // 136*32768 = 4,456,448 B
    float*    b2     = (float*)(ws + 4456448);              // 16 KB
    int*      bestIdx= (int*)(ws + 4472832);                // 256 KB
    int*      flagCnt= (int*)(ws + 4734976);                // 16 B
    int*      flagList=(int*)(ws + 4734992);                // 256 KB

    hipMemsetAsync(flagCnt, 0, sizeof(int), stream);
    b2_kernel    <<<dim3(1024), dim3(256), 0, stream>>>(cb, b2);
    pack_cb      <<<dim3(512),  dim3(256), 0, stream>>>(cb, cbws);
    pack_b2      <<<dim3(16),   dim3(256), 0, stream>>>(b2, cbws);
    argmin_kernel<<<dim3(N_TOK / BN), dim3(512), 0, stream>>>(x, cbws, bestIdx, flagCnt, flagList);
    refine_kernel<<<dim3(128),  dim3(256), 0, stream>>>(x, cb, flagCnt, flagList, bestIdx);
    gather_kernel<<<dim3(N_TOK * 64 / 256), dim3(256), 0, stream>>>(cb, bestIdx, out);
}

// Round 3
// 656.465 us; speedup vs baseline: 5.1836x; 5.1836x over previous
//
#include <hip/hip_runtime.h>
#include <cstdint>

typedef __attribute__((ext_vector_type(8)))  __bf16 v8bf;
typedef __attribute__((ext_vector_type(16))) float  v16f;
typedef unsigned short ushort_t;

#define N_TOK  65536
#define DIM    256
#define K_CB   4096
#define BN     64          // tokens per block
#define KC     512         // codes per kc-iter (8 waves x 64)
#define NKCI   8           // K_CB / KC
#define MARGIN_S 2.0e-4f   // s-space margin == 4e-4 dist-space

#define MFMA(a,b,c) __builtin_amdgcn_mfma_f32_32x32x16_bf16(a,b,c,0,0,0)

static __device__ __forceinline__ void gl_lds16(const void* g, void* l) {
    __builtin_amdgcn_global_load_lds(
        (const __attribute__((address_space(1))) unsigned int*)g,
        (__attribute__((address_space(3))) unsigned int*)l, 16, 0, 0);
}

// ---------------------------------------------------------------- b2 = ||c_k||^2
__global__ void b2_kernel(const float* __restrict__ cb, float* __restrict__ b2) {
    int gid = blockIdx.x * blockDim.x + threadIdx.x;
    int w = gid >> 6, lane = gid & 63;
    if (w >= K_CB) return;
    float4 v = reinterpret_cast<const float4*>(cb + (size_t)w * DIM)[lane];
    float s = (v.x * v.x + v.y * v.y) + (v.z * v.z + v.w * v.w);
#pragma unroll
    for (int off = 1; off < 64; off <<= 1) s += __shfl_xor(s, off, 64);
    if (lane == 0) b2[w] = s;
}

// ---------------------------------------------------------------- pack cb -> bf16 hi/lo panels
// ws chunk layout (32 KB each, 136 chunks): [wid 8][hi 2KB: [dgrp 2][64 codes][8 d]][lo 2KB]
__global__ void pack_cb(const float* __restrict__ cb, ushort_t* __restrict__ cbws) {
    int gid = blockIdx.x * 256 + threadIdx.x;          // 0..131071
    int k = gid >> 5, grp = gid & 31;                  // grp = d/8
    int ci = grp >> 1, dgrp = grp & 1;
    int kci = k >> 9, code = k & 511;
    int wid_s = code >> 6, cloc = code & 63;
    const float* src = cb + (size_t)k * DIM + grp * 8;
    float4 v0 = *(const float4*)(src);
    float4 v1 = *(const float4*)(src + 4);
    float f[8] = {v0.x, v0.y, v0.z, v0.w, v1.x, v1.y, v1.z, v1.w};
    v8bf hv, lv;
#pragma unroll
    for (int e = 0; e < 8; ++e) {
        __bf16 h = (__bf16)f[e];
        hv[e] = h;
        lv[e] = (__bf16)(f[e] - (float)h);
    }
    size_t base = ((size_t)(kci * 17 + ci)) * 16384 + wid_s * 2048 + dgrp * 512 + cloc * 8;
    *(v8bf*)(cbws + base)        = hv;
    *(v8bf*)(cbws + base + 1024) = lv;
}

// ---------------------------------------------------------------- pack b2 chunk (ci = 16)
__global__ void pack_b2(const float* __restrict__ b2, ushort_t* __restrict__ cbws) {
    int k = blockIdx.x * 256 + threadIdx.x;
    if (k >= K_CB) return;
    int kci = k >> 9, code = k & 511;
    int wid_s = code >> 6, cloc = code & 63;
    float v = -0.5f * b2[k];
    __bf16 h = (__bf16)v;
    __bf16 l = (__bf16)(v - (float)h);
    v8bf hv, zv;
#pragma unroll
    for (int e = 0; e < 8; ++e) { hv[e] = (__bf16)0.0f; zv[e] = (__bf16)0.0f; }
    hv[0] = h; hv[1] = l;
    size_t base = ((size_t)(kci * 17 + 16)) * 16384 + wid_s * 2048 + cloc * 8;
    *(v8bf*)(cbws + base)        = hv;   // hi dgrp0: k-slots 0,1 carry -b2/2 hi/lo
    *(v8bf*)(cbws + base + 512)  = zv;   // hi dgrp1
    *(v8bf*)(cbws + base + 1024) = zv;   // lo dgrp0
    *(v8bf*)(cbws + base + 1536) = zv;   // lo dgrp1
}

// ---------------------------------------------------------------- fused MFMA dist+argmax(s)
// s[n][k] = dot(x_n, c_k) - b2[k]/2 ; maximize s == minimize squared distance.
// All three bf16 products (xh*ch, xh*cl, xl*ch) accumulate into ONE fp32 acc.
__global__ __launch_bounds__(512, 2) void argmin_kernel(
    const float* __restrict__ x, const ushort_t* __restrict__ cbws,
    int* __restrict__ bestIdx, int* __restrict__ flagCnt, int* __restrict__ flagList)
{
    __shared__ __align__(16) ushort_t Xh[32 * 64 * 8];   // 32 KB: [dgrp 32][token 64][8 d]
    __shared__ __align__(16) ushort_t Xl[32 * 64 * 8];   // 32 KB
    __shared__ __align__(16) ushort_t Cs[3 * 8 * 2048];  // 96 KB: [ring 3][wid 8][4 KB slice]

    const int tid   = threadIdx.x;
    const int wid   = tid >> 6;
    const int lane  = tid & 63;
    const int l31   = lane & 31;
    const int lhalf = lane >> 5;
    const int n0    = blockIdx.x * BN;

    // ---- stage x tile (once): fp32 -> hi/lo bf16, d-subtiled
    {
        const int token = tid >> 3, dseg = tid & 7;
        const float4* xr = (const float4*)(x + (size_t)(n0 + token) * DIM + dseg * 32);
#pragma unroll
        for (int sgrp = 0; sgrp < 4; ++sgrp) {
            float4 a = xr[2 * sgrp], b = xr[2 * sgrp + 1];
            float f[8] = {a.x, a.y, a.z, a.w, b.x, b.y, b.z, b.w};
            v8bf hv, lv;
#pragma unroll
            for (int e = 0; e < 8; ++e) {
                __bf16 h = (__bf16)f[e];
                hv[e] = h; lv[e] = (__bf16)(f[e] - (float)h);
            }
            int off = ((dseg * 4 + sgrp) * 64 + token) * 8;
            *(v8bf*)(Xh + off) = hv;
            *(v8bf*)(Xl + off) = lv;
        }
    }

    // constant B-frag for the b2 chunk: B[k][n] = 1.0 at k-slots 0,1
    v8bf b17;
#pragma unroll
    for (int e = 0; e < 8; ++e) b17[e] = (__bf16)0.0f;
    if (lhalf == 0) { b17[0] = (__bf16)1.0f; b17[1] = (__bf16)1.0f; }

    const char* wsrc = (const char*)cbws + (size_t)wid * 4096 + (size_t)lane * 16;
    char* csb = (char*)Cs + (size_t)wid * 4096;
#define STAGE(c, s) do { \
        const char* sp_ = wsrc + (size_t)(c) * 32768; \
        char* dp_ = csb + (size_t)(s) * 32768; \
        gl_lds16(sp_, dp_); gl_lds16(sp_ + 1024, dp_ + 1024); \
        gl_lds16(sp_ + 2048, dp_ + 2048); gl_lds16(sp_ + 3072, dp_ + 3072); } while (0)

    asm volatile("s_waitcnt vmcnt(0)" ::: "memory");   // clean vmcnt baseline (x loads drained)
    STAGE(0, 0); STAGE(1, 1); STAGE(2, 2);
    asm volatile("s_waitcnt lgkmcnt(0)" ::: "memory"); // x ds_writes done
    __builtin_amdgcn_s_barrier();                      // Xh/Xl visible to all waves
    __builtin_amdgcn_sched_barrier(0);

    v16f vzero;
#pragma unroll
    for (int r = 0; r < 16; ++r) vzero[r] = 0.0f;
    v16f acc[2][2];
#pragma unroll
    for (int a = 0; a < 2; ++a)
#pragma unroll
        for (int b = 0; b < 2; ++b) acc[a][b] = vzero;

    float b1d[2] = {-3.0e38f, -3.0e38f}, b2d[2] = {-3.0e38f, -3.0e38f};
    int   b1i[2] = {0x7fffffff, 0x7fffffff};
    const int klh = 4 * lhalf;

    int g = 0, slot = 0;
#pragma unroll 1
    for (int kci = 0; kci < NKCI; ++kci) {
#pragma unroll 1
        for (int ci = 0; ci < 17; ++ci, ++g) {
            // wait for own chunk g (counted vmcnt; waves are barrier-free)
            if (g <= 133)      asm volatile("s_waitcnt vmcnt(8)" ::: "memory");
            else if (g == 134) asm volatile("s_waitcnt vmcnt(4)" ::: "memory");
            else               asm volatile("s_waitcnt vmcnt(0)" ::: "memory");
            __builtin_amdgcn_sched_barrier(0);   // don't hoist ds_reads above the wait

            const ushort_t* sl = Cs + ((size_t)slot * 8 + wid) * 2048;
            const int aoff = lhalf * 512 + l31 * 8;
            if (ci < 16) {
                v8bf ah0 = *(const v8bf*)(sl + aoff);
                v8bf ah1 = *(const v8bf*)(sl + aoff + 256);
                v8bf al0 = *(const v8bf*)(sl + 1024 + aoff);
                v8bf al1 = *(const v8bf*)(sl + 1024 + aoff + 256);
                const int boff = ((ci * 2 + lhalf) * 64 + l31) * 8;
                v8bf bh0 = *(const v8bf*)(Xh + boff);
                v8bf bh1 = *(const v8bf*)(Xh + boff + 256);
                v8bf bl0 = *(const v8bf*)(Xl + boff);
                v8bf bl1 = *(const v8bf*)(Xl + boff + 256);
                acc[0][0] = MFMA(ah0, bh0, acc[0][0]);
                acc[0][1] = MFMA(ah0, bh1, acc[0][1]);
                acc[1][0] = MFMA(ah1, bh0, acc[1][0]);
                acc[1][1] = MFMA(ah1, bh1, acc[1][1]);
                acc[0][0] = MFMA(ah0, bl0, acc[0][0]);
                acc[0][1] = MFMA(ah0, bl1, acc[0][1]);
                acc[1][0] = MFMA(ah1, bl0, acc[1][0]);
                acc[1][1] = MFMA(ah1, bl1, acc[1][1]);
                acc[0][0] = MFMA(al0, bh0, acc[0][0]);
                acc[0][1] = MFMA(al0, bh1, acc[0][1]);
                acc[1][0] = MFMA(al1, bh0, acc[1][0]);
                acc[1][1] = MFMA(al1, bh1, acc[1][1]);
            } else {   // b2 chunk: adds -b2[k]/2 (hi+lo in k-slots 0,1) to every column
                v8bf ah0 = *(const v8bf*)(sl + aoff);
                v8bf ah1 = *(const v8bf*)(sl + aoff + 256);
                acc[0][0] = MFMA(ah0, b17, acc[0][0]);
                acc[0][1] = MFMA(ah0, b17, acc[0][1]);
                acc[1][0] = MFMA(ah1, b17, acc[1][0]);
                acc[1][1] = MFMA(ah1, b17, acc[1][1]);
            }
            __builtin_amdgcn_sched_barrier(0);
            if (g <= 132) STAGE(g + 3, slot);   // refill the slot just consumed
            slot = (slot == 2) ? 0 : slot + 1;
        }
        // ---- fold this kc-chunk into running top-2 (pure registers), reset acc
        const int kbase = kci * KC + wid * 64 + klh;
#pragma unroll
        for (int fm = 0; fm < 2; ++fm)
#pragma unroll
        for (int j = 0; j < 2; ++j) {
#pragma unroll
            for (int r = 0; r < 16; ++r) {
                float sv = acc[fm][j][r];
                int k = kbase + fm * 32 + ((r & 3) + 8 * (r >> 2));
                bool better = (sv > b1d[j]) || (sv == b1d[j] && k < b1i[j]);
                b2d[j] = better ? b1d[j] : fmaxf(b2d[j], sv);
                b1d[j] = better ? sv : b1d[j];
                b1i[j] = better ? k : b1i[j];
            }
            acc[fm][j] = vzero;
        }
    }

    // ---- merge lane halves (same token lives in lane and lane^32)
#pragma unroll
    for (int j = 0; j < 2; ++j) {
        float o1 = __shfl_xor(b1d[j], 32);
        float o2 = __shfl_xor(b2d[j], 32);
        int   oi = __shfl_xor(b1i[j], 32);
        bool ow = (o1 > b1d[j]) || (o1 == b1d[j] && oi < b1i[j]);
        float nb2 = fmaxf(fminf(b1d[j], o1), fmaxf(b2d[j], o2));
        b1i[j] = ow ? oi : b1i[j];
        b1d[j] = fmaxf(b1d[j], o1);
        b2d[j] = nb2;
    }

    __syncthreads();
    float* f1 = (float*)Xh;          // [8 waves][64 tokens]
    float* f2 = f1 + 512;
    int*   fi = (int*)(f2 + 512);
    if (lane < 32) {
#pragma unroll
        for (int j = 0; j < 2; ++j) {
            int idx = wid * 64 + j * 32 + l31;
            f1[idx] = b1d[j]; f2[idx] = b2d[j]; fi[idx] = b1i[j];
        }
    }
    __syncthreads();
    if (tid < BN) {
        float s1 = -3.0e38f, s2 = -3.0e38f; int si = 0x7fffffff;
#pragma unroll
        for (int w = 0; w < 8; ++w) {
            float c1 = f1[w * 64 + tid], c2 = f2[w * 64 + tid];
            int  ci1 = fi[w * 64 + tid];
            bool ow = (c1 > s1) || (c1 == s1 && ci1 < si);
            float nb2 = fmaxf(fminf(s1, c1), fmaxf(s2, c2));
            si = ow ? ci1 : si; s1 = fmaxf(s1, c1); s2 = nb2;
        }
        int n = n0 + tid;
        bestIdx[n] = si;
        if (s1 - s2 < MARGIN_S) {            // dist gap < 4e-4 -> exact re-resolve
            int pos = atomicAdd(flagCnt, 1);
            flagList[pos] = n;
        }
    }
}

// ---------------------------------------------------------------- fp64 exact refine
__global__ void refine_kernel(const float* __restrict__ x, const float* __restrict__ cb,
                              const int* __restrict__ flagCnt, const int* __restrict__ flagList,
                              int* __restrict__ bestIdx)
{
    __shared__ float  xr[DIM];
    __shared__ double rd[256];
    __shared__ int    ri[256];
    const int tid = threadIdx.x;
    const int cnt = *flagCnt;
    for (int f = blockIdx.x; f < cnt; f += gridDim.x) {
        const int n = flagList[f];
        __syncthreads();
        if (tid < DIM / 4) {
            float4 v = reinterpret_cast<const float4*>(x + (size_t)n * DIM)[tid];
            xr[tid * 4 + 0] = v.x; xr[tid * 4 + 1] = v.y;
            xr[tid * 4 + 2] = v.z; xr[tid * 4 + 3] = v.w;
        }
        __syncthreads();
        double best = 1e300; int bi = K_CB;
        for (int k = tid; k < K_CB; k += 256) {
            const float* crow = cb + (size_t)k * DIM;
            double dot = 0.0, nb = 0.0;
            for (int d = 0; d < DIM; d += 4) {
                float4 cv = *reinterpret_cast<const float4*>(crow + d);
                dot += (double)cv.x * xr[d]     + (double)cv.y * xr[d + 1]
                     + (double)cv.z * xr[d + 2] + (double)cv.w * xr[d + 3];
                nb  += (double)cv.x * cv.x + (double)cv.y * cv.y
                     + (double)cv.z * cv.z + (double)cv.w * cv.w;
            }
            double dist = nb - 2.0 * dot;
            if (dist < best || (dist == best && k < bi)) { best = dist; bi = k; }
        }
        rd[tid] = best; ri[tid] = bi;
        __syncthreads();
        for (int s = 128; s > 0; s >>= 1) {
            if (tid < s) {
                double od = rd[tid + s]; int oi = ri[tid + s];
                if (od < rd[tid] || (od == rd[tid] && oi < ri[tid])) { rd[tid] = od; ri[tid] = oi; }
            }
            __syncthreads();
        }
        if (tid == 0) bestIdx[n] = ri[0];
        __syncthreads();
    }
}

// ---------------------------------------------------------------- gather out rows
__global__ void gather_kernel(const float* __restrict__ cb, const int* __restrict__ bestIdx,
                              float* __restrict__ out)
{
    int t = blockIdx.x * 256 + threadIdx.x;
    int n = t >> 6, f4 = t & 63;
    int k = bestIdx[n];
    reinterpret_cast<float4*>(out)[t] =
        reinterpret_cast<const float4*>(cb + (size_t)k * DIM)[f4];
}

extern "C" void kernel_launch(void* const* d_in, const int* in_sizes, int n_in,
                              void* d_out, int out_size, void* d_ws, size_t ws_size,
                              hipStream_t stream)
{
    const float* x  = (const float*)d_in[0];
    const float* cb = (const float*)d_in[1];
    float* out = (float*)d_out;

    char* ws = (char*)d_ws;
    ushort_t* cbws   = (ushort_t*)ws;                       // 136*32768 = 4,456,448 B
    float*    b2     = (float*)(ws + 4456448);              // 16 KB
    int*      bestIdx= (int*)(ws + 4472832);                // 256 KB
    int*      flagCnt= (int*)(ws + 4734976);                // 16 B
    int*      flagList=(int*)(ws + 4734992);                // 256 KB

    hipMemsetAsync(flagCnt, 0, sizeof(int), stream);
    b2_kernel    <<<dim3(1024), dim3(256), 0, stream>>>(cb, b2);
    pack_cb      <<<dim3(512),  dim3(256), 0, stream>>>(cb, cbws);
    pack_b2      <<<dim3(16),   dim3(256), 0, stream>>>(b2, cbws);
    argmin_kernel<<<dim3(N_TOK / BN), dim3(512), 0, stream>>>(x, cbws, bestIdx, flagCnt, flagList);
    refine_kernel<<<dim3(128),  dim3(256), 0, stream>>>(x, cb, flagCnt, flagList, bestIdx);
    gather_kernel<<<dim3(N_TOK * 64 / 256), dim3(256), 0, stream>>>(cb, bestIdx, out);
}

// Round 4
// 555.880 us; speedup vs baseline: 6.1216x; 1.1809x over previous
//
#include <hip/hip_runtime.h>
#include <cstdint>

typedef __attribute__((ext_vector_type(8)))  __bf16 v8bf;
typedef __attribute__((ext_vector_type(16))) float  v16f;
typedef unsigned short ushort_t;

#define N_TOK  65536
#define DIM    256
#define K_CB   4096
#define BN     64          // tokens per block
#define KC     512         // codes per kc-iter (8 waves x 64)
#define NKCI   8           // K_CB / KC
#define NCHUNK 128         // NKCI * 16 d-chunks
#define MARGIN_S 2.0e-4f   // s-space margin == 4e-4 dist-space

#define MFMA(a,b,c) __builtin_amdgcn_mfma_f32_32x32x16_bf16(a,b,c,0,0,0)

// ---------------------------------------------------------------- b2 = ||c_k||^2
__global__ void b2_kernel(const float* __restrict__ cb, float* __restrict__ b2) {
    int gid = blockIdx.x * blockDim.x + threadIdx.x;
    int w = gid >> 6, lane = gid & 63;
    if (w >= K_CB) return;
    float4 v = reinterpret_cast<const float4*>(cb + (size_t)w * DIM)[lane];
    float s = (v.x * v.x + v.y * v.y) + (v.z * v.z + v.w * v.w);
#pragma unroll
    for (int off = 1; off < 64; off <<= 1) s += __shfl_xor(s, off, 64);
    if (lane == 0) b2[w] = s;
}

// ---------------------------------------------------------------- pack cb -> bf16 hi/lo panels
// chunk = (kci*16 + ci), 32 KB each: [wave 8][hi 2KB: [dgrp 2][64 codes][8 d]][lo 2KB]
__global__ void pack_cb(const float* __restrict__ cb, ushort_t* __restrict__ cbws) {
    int gid = blockIdx.x * 256 + threadIdx.x;          // 0..131071
    int k = gid >> 5, grp = gid & 31;                  // grp = d/8
    int ci = grp >> 1, dgrp = grp & 1;
    int kci = k >> 9, code = k & 511;
    int wid_s = code >> 6, cloc = code & 63;
    const float* src = cb + (size_t)k * DIM + grp * 8;
    float4 v0 = *(const float4*)(src);
    float4 v1 = *(const float4*)(src + 4);
    float f[8] = {v0.x, v0.y, v0.z, v0.w, v1.x, v1.y, v1.z, v1.w};
    v8bf hv, lv;
#pragma unroll
    for (int e = 0; e < 8; ++e) {
        __bf16 h = (__bf16)f[e];
        hv[e] = h;
        lv[e] = (__bf16)(f[e] - (float)h);
    }
    size_t base = ((size_t)(kci * 16 + ci)) * 16384 + wid_s * 2048 + dgrp * 512 + cloc * 8;
    *(v8bf*)(cbws + base)        = hv;
    *(v8bf*)(cbws + base + 1024) = lv;
}

// ---------------------------------------------------------------- fused MFMA dist+argmax(s)
// s[n][k] = dot(x_n, c_k); fold subtracts b2[k]/2 in fp32. argmax s == argmin dist.
__global__ __launch_bounds__(512, 2) void argmin_kernel(
    const float* __restrict__ x, const ushort_t* __restrict__ cbws,
    const float* __restrict__ b2, int* __restrict__ bestIdx,
    int* __restrict__ flagCnt, int* __restrict__ flagList)
{
    __shared__ __align__(16) ushort_t Xh[32 * 64 * 8];   // 32 KB: [dgrp 32][token 64][8 d]
    __shared__ __align__(16) ushort_t Xl[32 * 64 * 8];   // 32 KB

    const int tid   = threadIdx.x;
    const int wid   = tid >> 6;
    const int lane  = tid & 63;
    const int l31   = lane & 31;
    const int lhalf = lane >> 5;
    const int n0    = blockIdx.x * BN;

    // ---- stage x tile (once): fp32 -> hi/lo bf16, d-subtiled
    {
        const int token = tid >> 3, dseg = tid & 7;
        const float4* xr = (const float4*)(x + (size_t)(n0 + token) * DIM + dseg * 32);
#pragma unroll
        for (int sgrp = 0; sgrp < 4; ++sgrp) {
            float4 a = xr[2 * sgrp], b = xr[2 * sgrp + 1];
            float f[8] = {a.x, a.y, a.z, a.w, b.x, b.y, b.z, b.w};
            v8bf hv, lv;
#pragma unroll
            for (int e = 0; e < 8; ++e) {
                __bf16 h = (__bf16)f[e];
                hv[e] = h; lv[e] = (__bf16)(f[e] - (float)h);
            }
            int off = ((dseg * 4 + sgrp) * 64 + token) * 8;
            *(v8bf*)(Xh + off) = hv;
            *(v8bf*)(Xl + off) = lv;
        }
    }
    __syncthreads();

    // per-lane A source: wave slice base + lane offset; chunk stride 16384 ushorts
    const int aoff = lhalf * 512 + l31 * 8;
    const ushort_t* ap = cbws + (size_t)wid * 2048 + aoff;

#define LOAD_A(A, g_) do { \
        const ushort_t* p_ = ap + (size_t)(g_) * 16384; \
        A##0 = *(const v8bf*)(p_);        A##1 = *(const v8bf*)(p_ + 256); \
        A##2 = *(const v8bf*)(p_ + 1024); A##3 = *(const v8bf*)(p_ + 1280); } while (0)
#define READ_B(B, g_) do { \
        int boff_ = ((((g_) & 15) * 2 + lhalf) * 64 + l31) * 8; \
        B##0 = *(const v8bf*)(Xh + boff_); B##1 = *(const v8bf*)(Xh + boff_ + 256); \
        B##2 = *(const v8bf*)(Xl + boff_); B##3 = *(const v8bf*)(Xl + boff_ + 256); } while (0)
#define MFMA12(A, B) do { \
        acc[0][0] = MFMA(A##0, B##0, acc[0][0]); \
        acc[0][1] = MFMA(A##0, B##1, acc[0][1]); \
        acc[1][0] = MFMA(A##1, B##0, acc[1][0]); \
        acc[1][1] = MFMA(A##1, B##1, acc[1][1]); \
        acc[0][0] = MFMA(A##0, B##2, acc[0][0]); \
        acc[0][1] = MFMA(A##0, B##3, acc[0][1]); \
        acc[1][0] = MFMA(A##1, B##2, acc[1][0]); \
        acc[1][1] = MFMA(A##1, B##3, acc[1][1]); \
        acc[0][0] = MFMA(A##2, B##0, acc[0][0]); \
        acc[0][1] = MFMA(A##2, B##1, acc[0][1]); \
        acc[1][0] = MFMA(A##3, B##0, acc[1][0]); \
        acc[1][1] = MFMA(A##3, B##1, acc[1][1]); } while (0)

    v16f vzero;
#pragma unroll
    for (int r = 0; r < 16; ++r) vzero[r] = 0.0f;
    v16f acc[2][2];
#pragma unroll
    for (int a = 0; a < 2; ++a)
#pragma unroll
        for (int b = 0; b < 2; ++b) acc[a][b] = vzero;

    float b1d[2] = {-3.0e38f, -3.0e38f}, b2d[2] = {-3.0e38f, -3.0e38f};
    int   b1i[2] = {0x7fffffff, 0x7fffffff};

    v8bf Aa0, Aa1, Aa2, Aa3, Ab0, Ab1, Ab2, Ab3;
    v8bf Ba0, Ba1, Ba2, Ba3, Bb0, Bb1, Bb2, Bb3;

    LOAD_A(Aa, 0); READ_B(Ba, 0);

#pragma unroll 1
    for (int g = 0; g < NCHUNK; g += 2) {
        LOAD_A(Ab, g + 1); READ_B(Bb, g + 1);
        MFMA12(Aa, Ba);
        if (g + 2 < NCHUNK) { LOAD_A(Aa, g + 2); READ_B(Ba, g + 2); }
        MFMA12(Ab, Bb);

        if ((g & 15) == 14) {       // ---- fold kci into running top-2, reset acc
            const int kci = g >> 4;
            const float* bp = b2 + (kci << 9) + wid * 64 + 4 * lhalf;
#pragma unroll
            for (int fm = 0; fm < 2; ++fm) {
                float4 q0 = *(const float4*)(bp + fm * 32);
                float4 q1 = *(const float4*)(bp + fm * 32 + 8);
                float4 q2 = *(const float4*)(bp + fm * 32 + 16);
                float4 q3 = *(const float4*)(bp + fm * 32 + 24);
                float bw[16] = {q0.x, q0.y, q0.z, q0.w, q1.x, q1.y, q1.z, q1.w,
                                q2.x, q2.y, q2.z, q2.w, q3.x, q3.y, q3.z, q3.w};
                const int kbase = (kci << 9) + wid * 64 + fm * 32 + 4 * lhalf;
#pragma unroll
                for (int j = 0; j < 2; ++j) {
#pragma unroll
                    for (int r = 0; r < 16; ++r) {
                        float sv = fmaf(-0.5f, bw[r], acc[fm][j][r]);
                        int k = kbase + (r & 3) + 8 * (r >> 2);
                        bool better = (sv > b1d[j]) || (sv == b1d[j] && k < b1i[j]);
                        b2d[j] = better ? b1d[j] : fmaxf(b2d[j], sv);
                        b1d[j] = better ? sv : b1d[j];
                        b1i[j] = better ? k : b1i[j];
                    }
                    acc[fm][j] = vzero;
                }
            }
        }
    }

    // ---- merge lane halves (same token lives in lane and lane^32)
#pragma unroll
    for (int j = 0; j < 2; ++j) {
        float o1 = __shfl_xor(b1d[j], 32);
        float o2 = __shfl_xor(b2d[j], 32);
        int   oi = __shfl_xor(b1i[j], 32);
        bool ow = (o1 > b1d[j]) || (o1 == b1d[j] && oi < b1i[j]);
        float nb2 = fmaxf(fminf(b1d[j], o1), fmaxf(b2d[j], o2));
        b1i[j] = ow ? oi : b1i[j];
        b1d[j] = fmaxf(b1d[j], o1);
        b2d[j] = nb2;
    }

    __syncthreads();
    float* f1 = (float*)Xh;          // [8 waves][64 tokens]
    float* f2 = f1 + 512;
    int*   fi = (int*)(f2 + 512);
    if (lane < 32) {
#pragma unroll
        for (int j = 0; j < 2; ++j) {
            int idx = wid * 64 + j * 32 + l31;
            f1[idx] = b1d[j]; f2[idx] = b2d[j]; fi[idx] = b1i[j];
        }
    }
    __syncthreads();
    if (tid < BN) {
        float s1 = -3.0e38f, s2 = -3.0e38f; int si = 0x7fffffff;
#pragma unroll
        for (int w = 0; w < 8; ++w) {
            float c1 = f1[w * 64 + tid], c2 = f2[w * 64 + tid];
            int  ci1 = fi[w * 64 + tid];
            bool ow = (c1 > s1) || (c1 == s1 && ci1 < si);
            float nb2 = fmaxf(fminf(s1, c1), fmaxf(s2, c2));
            si = ow ? ci1 : si; s1 = fmaxf(s1, c1); s2 = nb2;
        }
        int n = n0 + tid;
        bestIdx[n] = si;
        if (s1 - s2 < MARGIN_S) {            // dist gap < 4e-4 -> exact re-resolve
            int pos = atomicAdd(flagCnt, 1);
            flagList[pos] = n;
        }
    }
}

// ---------------------------------------------------------------- fp64 exact refine
__global__ void refine_kernel(const float* __restrict__ x, const float* __restrict__ cb,
                              const int* __restrict__ flagCnt, const int* __restrict__ flagList,
                              int* __restrict__ bestIdx)
{
    __shared__ float  xr[DIM];
    __shared__ double rd[256];
    __shared__ int    ri[256];
    const int tid = threadIdx.x;
    const int cnt = *flagCnt;
    for (int f = blockIdx.x; f < cnt; f += gridDim.x) {
        const int n = flagList[f];
        __syncthreads();
        if (tid < DIM / 4) {
            float4 v = reinterpret_cast<const float4*>(x + (size_t)n * DIM)[tid];
            xr[tid * 4 + 0] = v.x; xr[tid * 4 + 1] = v.y;
            xr[tid * 4 + 2] = v.z; xr[tid * 4 + 3] = v.w;
        }
        __syncthreads();
        double best = 1e300; int bi = K_CB;
        for (int k = tid; k < K_CB; k += 256) {
            const float* crow = cb + (size_t)k * DIM;
            double dot = 0.0, nb = 0.0;
            for (int d = 0; d < DIM; d += 4) {
                float4 cv = *reinterpret_cast<const float4*>(crow + d);
                dot += (double)cv.x * xr[d]     + (double)cv.y * xr[d + 1]
                     + (double)cv.z * xr[d + 2] + (double)cv.w * xr[d + 3];
                nb  += (double)cv.x * cv.x + (double)cv.y * cv.y
                     + (double)cv.z * cv.z + (double)cv.w * cv.w;
            }
            double dist = nb - 2.0 * dot;
            if (dist < best || (dist == best && k < bi)) { best = dist; bi = k; }
        }
        rd[tid] = best; ri[tid] = bi;
        __syncthreads();
        for (int s = 128; s > 0; s >>= 1) {
            if (tid < s) {
                double od = rd[tid + s]; int oi = ri[tid + s];
                if (od < rd[tid] || (od == rd[tid] && oi < ri[tid])) { rd[tid] = od; ri[tid] = oi; }
            }
            __syncthreads();
        }
        if (tid == 0) bestIdx[n] = ri[0];
        __syncthreads();
    }
}

// ---------------------------------------------------------------- gather out rows
__global__ void gather_kernel(const float* __restrict__ cb, const int* __restrict__ bestIdx,
                              float* __restrict__ out)
{
    int t = blockIdx.x * 256 + threadIdx.x;
    int n = t >> 6, f4 = t & 63;
    int k = bestIdx[n];
    reinterpret_cast<float4*>(out)[t] =
        reinterpret_cast<const float4*>(cb + (size_t)k * DIM)[f4];
}

extern "C" void kernel_launch(void* const* d_in, const int* in_sizes, int n_in,
                              void* d_out, int out_size, void* d_ws, size_t ws_size,
                              hipStream_t stream)
{
    const float* x  = (const float*)d_in[0];
    const float* cb = (const float*)d_in[1];
    float* out = (float*)d_out;

    char* ws = (char*)d_ws;
    ushort_t* cbws    = (ushort_t*)ws;                      // 128*32768 = 4,194,304 B
    float*    b2      = (float*)(ws + 4194304);             // 16 KB
    int*      bestIdx = (int*)(ws + 4210688);               // 256 KB
    int*      flagCnt = (int*)(ws + 4472832);               // 16 B
    int*      flagList= (int*)(ws + 4472848);               // 256 KB

    hipMemsetAsync(flagCnt, 0, sizeof(int), stream);
    b2_kernel    <<<dim3(1024), dim3(256), 0, stream>>>(cb, b2);
    pack_cb      <<<dim3(512),  dim3(256), 0, stream>>>(cb, cbws);
    argmin_kernel<<<dim3(N_TOK / BN), dim3(512), 0, stream>>>(x, cbws, b2, bestIdx, flagCnt, flagList);
    refine_kernel<<<dim3(128),  dim3(256), 0, stream>>>(x, cb, flagCnt, flagList, bestIdx);
    gather_kernel<<<dim3(N_TOK * 64 / 256), dim3(256), 0, stream>>>(cb, bestIdx, out);
}